// Round 1
// baseline (1972.114 us; speedup 1.0000x reference)
//
#include <hip/hip_runtime.h>
#include <math.h>

#define NN   50000
#define NE   500000
#define NTT  10000
#define ETT  100000
#define HF   320      // h_final row = 128 + 3*64
#define EFW  160      // e_final row = 64 + 3*32

__device__ __forceinline__ float silu_f(float x) { return x / (1.f + __expf(-x)); }

// ---------------- K0: fold W_nsp into W_left / W_right ----------------
__global__ __launch_bounds__(256) void k0_combine(
    const float* __restrict__ W_nsp, const float* __restrict__ b_nsp,
    const float* __restrict__ W_left, const float* __restrict__ b_left,
    const float* __restrict__ W_right, const float* __restrict__ b_right,
    float* __restrict__ Wl, float* __restrict__ bl,
    float* __restrict__ Wr, float* __restrict__ br)
{
    int idx = blockIdx.x * 256 + threadIdx.x;   // 0..16383
    int i = idx >> 7, j = idx & 127;
    float al = 0.f, ar = 0.f;
    for (int k = 0; k < 128; ++k) {
        float w = W_nsp[i * 128 + k];
        al = fmaf(w, W_left[k * 128 + j], al);
        ar = fmaf(w, W_right[k * 128 + j], ar);
    }
    Wl[idx] = al; Wr[idx] = ar;
    if (i == 0) {
        float cl = 0.f, cr = 0.f;
        for (int k = 0; k < 128; ++k) {
            float bn = b_nsp[k];
            cl = fmaf(bn, W_left[k * 128 + j], cl);
            cr = fmaf(bn, W_right[k * 128 + j], cr);
        }
        bl[j] = cl + b_left[j];
        br[j] = cr + b_right[j];
    }
}

// ---------------- K1: hl/hr for all nodes ----------------
__global__ __launch_bounds__(256) void k1_nodeproj(
    const float* __restrict__ h_final,
    const float* __restrict__ Wl, const float* __restrict__ bl,
    const float* __restrict__ Wr, const float* __restrict__ br,
    float* __restrict__ hl, float* __restrict__ hr)
{
    __shared__ float sWl[16384];
    __shared__ float sWr[16384];
    __shared__ float sx[8][128];
    const int tid = threadIdx.x;
    for (int i = tid; i < 16384; i += 256) { sWl[i] = Wl[i]; sWr[i] = Wr[i]; }
    const int j = tid & 127;
    const int sub = tid >> 7;
    const float blj = bl[j], brj = br[j];
    for (int base = blockIdx.x * 8; base < NN; base += gridDim.x * 8) {
        __syncthreads();
        #pragma unroll
        for (int t = tid; t < 1024; t += 256) {
            int n = t >> 7;
            sx[n][t & 127] = h_final[(size_t)(base + n) * HF + (t & 127)];
        }
        __syncthreads();
        const int n0 = sub * 4;
        float accl[4] = {0.f,0.f,0.f,0.f}, accr[4] = {0.f,0.f,0.f,0.f};
        for (int k = 0; k < 128; ++k) {
            float wl = sWl[k * 128 + j], wr = sWr[k * 128 + j];
            #pragma unroll
            for (int u = 0; u < 4; ++u) {
                float xv = sx[n0 + u][k];
                accl[u] = fmaf(xv, wl, accl[u]);
                accr[u] = fmaf(xv, wr, accr[u]);
            }
        }
        #pragma unroll
        for (int u = 0; u < 4; ++u) {
            size_t n = (size_t)(base + n0 + u);
            hl[n * 128 + j] = accl[u] + blj;
            hr[n * 128 + j] = accr[u] + brj;
        }
    }
}

// ---------------- K2: atom-type head ----------------
__global__ __launch_bounds__(256) void k2_atom(
    const float* __restrict__ h_final, const int* __restrict__ tn,
    const float* __restrict__ W_nsp, const float* __restrict__ b_nsp,
    const float* __restrict__ W_at1, const float* __restrict__ b_at1,
    const float* __restrict__ W_at2, const float* __restrict__ b_at2,
    float* __restrict__ out)
{
    __shared__ float sW0[16384], sW1[16384], sW2[4096];
    __shared__ float sx[2][128], ss[2][128], sa[2][128];
    const int tid = threadIdx.x;
    for (int i = tid; i < 16384; i += 256) { sW0[i] = W_nsp[i]; sW1[i] = W_at1[i]; }
    for (int i = tid; i < 4096; i += 256) sW2[i] = W_at2[i];
    const int j = tid & 127, sub = tid >> 7;
    const float bn = b_nsp[j], ba1 = b_at1[j];
    const float ba2 = (j < 32) ? b_at2[j] : 0.f;
    for (int base = blockIdx.x * 2; base < NTT; base += gridDim.x * 2) {
        __syncthreads();
        const int t = base + sub;
        const int node = tn[t];
        sx[sub][j] = h_final[(size_t)node * HF + j];
        __syncthreads();
        float acc = 0.f;
        for (int k = 0; k < 128; ++k) acc = fmaf(sx[sub][k], sW0[k * 128 + j], acc);
        ss[sub][j] = acc + bn;
        __syncthreads();
        acc = 0.f;
        for (int k = 0; k < 128; ++k) acc = fmaf(ss[sub][k], sW1[k * 128 + j], acc);
        sa[sub][j] = silu_f(acc + ba1);
        __syncthreads();
        if (j < 32) {
            float o = 0.f;
            for (int k = 0; k < 128; ++k) o = fmaf(sa[sub][k], sW2[k * 32 + j], o);
            out[(size_t)t * 32 + j] = o + ba2;
        }
    }
}

// ---------------- K3: edge MLP + force accumulation ----------------
__global__ __launch_bounds__(512) void k3_edge(
    const float* __restrict__ e_final, const int* __restrict__ edge_index,
    const float* __restrict__ hl, const float* __restrict__ hr,
    const float* __restrict__ r_t,
    const float* __restrict__ W_el1, const float* __restrict__ b_el1,
    const float* __restrict__ ln_g, const float* __restrict__ ln_b,
    const float* __restrict__ W_el2, const float* __restrict__ b_el2,
    float* __restrict__ delta)
{
    __shared__ float sW[224 * 128];      // 114.7 KB
    __shared__ float sx[32][224];        // 28.7 KB
    const int tid = threadIdx.x;
    for (int i = tid; i < 224 * 128; i += 512) sW[i] = W_el1[i];
    const int j = tid & 31;              // output quad
    const int g = tid >> 5;              // group 0..15, 2 edges each
    float bj[4], gj[4], nbj[4], w2j[4];
    { float4 tv = *(const float4*)&b_el1[4 * j]; bj[0]=tv.x; bj[1]=tv.y; bj[2]=tv.z; bj[3]=tv.w; }
    { float4 tv = *(const float4*)&ln_g[4 * j];  gj[0]=tv.x; gj[1]=tv.y; gj[2]=tv.z; gj[3]=tv.w; }
    { float4 tv = *(const float4*)&ln_b[4 * j];  nbj[0]=tv.x; nbj[1]=tv.y; nbj[2]=tv.z; nbj[3]=tv.w; }
    { float4 tv = *(const float4*)&W_el2[4 * j]; w2j[0]=tv.x; w2j[1]=tv.y; w2j[2]=tv.z; w2j[3]=tv.w; }
    const float b2 = b_el2[0];
    for (int base = blockIdx.x * 32; base < NE; base += gridDim.x * 32) {
        __syncthreads();
        for (int idx = tid; idx < 32 * 64; idx += 512) {
            int e = idx >> 6, k = idx & 63;
            sx[e][k] = e_final[(size_t)(base + e) * EFW + k];
        }
        for (int idx = tid; idx < 32 * 32; idx += 512) {
            int e = idx >> 5, v = idx & 31;
            const float* p = &e_final[(size_t)(base + e) * EFW + 64 + v * 3];
            sx[e][64 + v] = sqrtf(p[0]*p[0] + p[1]*p[1] + p[2]*p[2]);
        }
        for (int idx = tid; idx < 32 * 128; idx += 512) {
            int e = idx >> 7, c = idx & 127;
            int ge = base + e;
            int r = edge_index[ge], cl = edge_index[NE + ge];
            sx[e][96 + c] = hl[(size_t)r * 128 + c] * hr[(size_t)cl * 128 + c];
        }
        __syncthreads();
        const int e0 = g * 2;
        float acc0[4] = {0,0,0,0}, acc1[4] = {0,0,0,0};
        #pragma unroll 4
        for (int k = 0; k < 224; k += 4) {
            float4 xa = *(const float4*)&sx[e0][k];
            float4 xb = *(const float4*)&sx[e0 + 1][k];
            const float xav[4] = {xa.x, xa.y, xa.z, xa.w};
            const float xbv[4] = {xb.x, xb.y, xb.z, xb.w};
            #pragma unroll
            for (int u = 0; u < 4; ++u) {
                float4 wv = *(const float4*)&sW[(k + u) * 128 + 4 * j];
                acc0[0] = fmaf(xav[u], wv.x, acc0[0]);
                acc0[1] = fmaf(xav[u], wv.y, acc0[1]);
                acc0[2] = fmaf(xav[u], wv.z, acc0[2]);
                acc0[3] = fmaf(xav[u], wv.w, acc0[3]);
                acc1[0] = fmaf(xbv[u], wv.x, acc1[0]);
                acc1[1] = fmaf(xbv[u], wv.y, acc1[1]);
                acc1[2] = fmaf(xbv[u], wv.z, acc1[2]);
                acc1[3] = fmaf(xbv[u], wv.w, acc1[3]);
            }
        }
        // bias + layernorm stats over 128 outputs (32 lanes x 4)
        float s0=0.f, q0=0.f, s1=0.f, q1=0.f;
        #pragma unroll
        for (int c = 0; c < 4; ++c) {
            float y0 = acc0[c] + bj[c]; acc0[c] = y0;
            float y1 = acc1[c] + bj[c]; acc1[c] = y1;
            s0 += y0; q0 = fmaf(y0, y0, q0);
            s1 += y1; q1 = fmaf(y1, y1, q1);
        }
        #pragma unroll
        for (int m = 16; m >= 1; m >>= 1) {
            s0 += __shfl_xor(s0, m); q0 += __shfl_xor(q0, m);
            s1 += __shfl_xor(s1, m); q1 += __shfl_xor(q1, m);
        }
        const float mu0 = s0 * (1.f/128.f), mu1 = s1 * (1.f/128.f);
        const float iv0 = rsqrtf(q0 * (1.f/128.f) - mu0*mu0 + 1e-5f);
        const float iv1 = rsqrtf(q1 * (1.f/128.f) - mu1*mu1 + 1e-5f);
        float p0 = 0.f, p1 = 0.f;
        #pragma unroll
        for (int c = 0; c < 4; ++c) {
            float a0 = (acc0[c] - mu0) * iv0 * gj[c] + nbj[c];
            float a1 = (acc1[c] - mu1) * iv1 * gj[c] + nbj[c];
            p0 = fmaf(silu_f(a0), w2j[c], p0);
            p1 = fmaf(silu_f(a1), w2j[c], p1);
        }
        #pragma unroll
        for (int m = 16; m >= 1; m >>= 1) { p0 += __shfl_xor(p0, m); p1 += __shfl_xor(p1, m); }
        if (j < 2) {
            int ge = base + e0 + j;
            float we = ((j == 0) ? p0 : p1) + b2;
            int r = edge_index[ge], cl = edge_index[NE + ge];
            float rx = r_t[r*3+0] - r_t[cl*3+0];
            float ry = r_t[r*3+1] - r_t[cl*3+1];
            float rz = r_t[r*3+2] - r_t[cl*3+2];
            float dist = sqrtf(rx*rx + ry*ry + rz*rz) + 1e-8f;
            float f = we / (dist * (dist + 1.f));
            atomicAdd(&delta[r*3+0], f*rx);
            atomicAdd(&delta[r*3+1], f*ry);
            atomicAdd(&delta[r*3+2], f*rz);
        }
    }
}

// ---------------- K4: tensor-product scalar per target edge ----------------
__global__ __launch_bounds__(256) void k4_tp(
    const float* __restrict__ h_final, const int* __restrict__ edge_index,
    const int* __restrict__ te,
    const float* __restrict__ w_tp0, const float* __restrict__ w_tp1,
    float* __restrict__ tp)
{
    __shared__ float sW0[128 * 129];     // padded: bank-conflict-free
    __shared__ float sW1[64 * 65];
    __shared__ float ssy[4][128];
    __shared__ float svy[4][64][4];
    const int tid = threadIdx.x;
    for (int i = tid; i < 128 * 128; i += 256) sW0[(i >> 7) * 129 + (i & 127)] = w_tp0[i];
    for (int i = tid; i < 64 * 64; i += 256)  sW1[(i >> 6) * 65 + (i & 63)] = w_tp1[i];
    const int w = tid >> 6, l = tid & 63;
    for (int base = blockIdx.x * 4; base < ETT; base += gridDim.x * 4) {
        __syncthreads();
        const int e = base + w;
        const bool act = (e < ETT);
        int r2 = 0;
        if (act) {
            int ge = te[e];
            r2 = edge_index[ge];
            int c2 = edge_index[NE + ge];
            const float* hc = &h_final[(size_t)c2 * HF];
            ssy[w][l] = hc[l];
            ssy[w][l + 64] = hc[l + 64];
            #pragma unroll
            for (int mm = 0; mm < 3; ++mm) {
                int m = l + mm * 64;
                svy[w][m / 3][m % 3] = hc[128 + m];
            }
        }
        __syncthreads();
        float res = 0.f;
        if (act) {
            const float* ha = &h_final[(size_t)r2 * HF];
            const float sx1 = ha[l], sx2 = ha[l + 64];
            float a1 = 0.f, a2 = 0.f;
            for (int jj = 0; jj < 128; ++jj) {
                float syv = ssy[w][jj];
                a1 = fmaf(sW0[l * 129 + jj], syv, a1);
                a2 = fmaf(sW0[(l + 64) * 129 + jj], syv, a2);
            }
            float sres = sx1 * a1 + sx2 * a2;
            const float vx0 = ha[128 + l*3 + 0];
            const float vx1 = ha[128 + l*3 + 1];
            const float vx2 = ha[128 + l*3 + 2];
            float t0 = 0.f, t1 = 0.f, t2 = 0.f;
            for (int jj = 0; jj < 64; ++jj) {
                float wv = sW1[l * 65 + jj];
                t0 = fmaf(wv, svy[w][jj][0], t0);
                t1 = fmaf(wv, svy[w][jj][1], t1);
                t2 = fmaf(wv, svy[w][jj][2], t2);
            }
            float vres = vx0*t0 + vx1*t1 + vx2*t2;
            res = sres * (1.f/128.f) + vres * (1.f/110.85125168440814f); // 64*sqrt(3)
        }
        #pragma unroll
        for (int m = 32; m >= 1; m >>= 1) res += __shfl_xor(res, m);
        if (act && l == 0) tp[e] = res;
    }
}

// ---------------- K5: bond head ----------------
__global__ __launch_bounds__(256) void k5_bond(
    const float* __restrict__ e_final, const int* __restrict__ te,
    const float* __restrict__ tp,
    const float* __restrict__ W_bh1, const float* __restrict__ b_bh1,
    const float* __restrict__ W_bh2, const float* __restrict__ b_bh2,
    float* __restrict__ out)
{
    __shared__ float sW[164 * 128];      // rows 161..163 zeroed
    __shared__ float sx[16][164];        // [161..163] zeroed
    const int tid = threadIdx.x;
    for (int i = tid; i < 161 * 128; i += 256) sW[i] = W_bh1[i];
    for (int i = tid; i < 3 * 128; i += 256) sW[161 * 128 + i] = 0.f;
    for (int i = tid; i < 16 * 3; i += 256) sx[i / 3][161 + (i % 3)] = 0.f;
    const int j = tid & 31, g = tid >> 5;
    float bj[4];
    { float4 tv = *(const float4*)&b_bh1[4 * j]; bj[0]=tv.x; bj[1]=tv.y; bj[2]=tv.z; bj[3]=tv.w; }
    float w2r[4][8], b2r[8];
    #pragma unroll
    for (int c = 0; c < 4; ++c)
        #pragma unroll
        for (int o = 0; o < 8; ++o) w2r[c][o] = W_bh2[(4*j + c) * 8 + o];
    #pragma unroll
    for (int o = 0; o < 8; ++o) b2r[o] = b_bh2[o];
    for (int base = blockIdx.x * 16; base < ETT; base += gridDim.x * 16) {
        __syncthreads();
        for (int idx = tid; idx < 16 * 161; idx += 256) {
            int e = idx / 161, k = idx - e * 161;
            sx[e][k] = (k == 0) ? tp[base + e]
                                : e_final[(size_t)te[base + e] * EFW + (k - 1)];
        }
        __syncthreads();
        const int e0 = g * 2;
        float acc0[4] = {0,0,0,0}, acc1[4] = {0,0,0,0};
        #pragma unroll 4
        for (int k = 0; k < 164; k += 4) {
            float4 xa = *(const float4*)&sx[e0][k];
            float4 xb = *(const float4*)&sx[e0 + 1][k];
            const float xav[4] = {xa.x, xa.y, xa.z, xa.w};
            const float xbv[4] = {xb.x, xb.y, xb.z, xb.w};
            #pragma unroll
            for (int u = 0; u < 4; ++u) {
                float4 wv = *(const float4*)&sW[(k + u) * 128 + 4 * j];
                acc0[0] = fmaf(xav[u], wv.x, acc0[0]);
                acc0[1] = fmaf(xav[u], wv.y, acc0[1]);
                acc0[2] = fmaf(xav[u], wv.z, acc0[2]);
                acc0[3] = fmaf(xav[u], wv.w, acc0[3]);
                acc1[0] = fmaf(xbv[u], wv.x, acc1[0]);
                acc1[1] = fmaf(xbv[u], wv.y, acc1[1]);
                acc1[2] = fmaf(xbv[u], wv.z, acc1[2]);
                acc1[3] = fmaf(xbv[u], wv.w, acc1[3]);
            }
        }
        float po0[8] = {0,0,0,0,0,0,0,0}, po1[8] = {0,0,0,0,0,0,0,0};
        #pragma unroll
        for (int c = 0; c < 4; ++c) {
            float a0 = silu_f(acc0[c] + bj[c]);
            float a1 = silu_f(acc1[c] + bj[c]);
            #pragma unroll
            for (int o = 0; o < 8; ++o) {
                po0[o] = fmaf(a0, w2r[c][o], po0[o]);
                po1[o] = fmaf(a1, w2r[c][o], po1[o]);
            }
        }
        #pragma unroll
        for (int m = 16; m >= 1; m >>= 1) {
            #pragma unroll
            for (int o = 0; o < 8; ++o) {
                po0[o] += __shfl_xor(po0[o], m);
                po1[o] += __shfl_xor(po1[o], m);
            }
        }
        if (j < 2) {
            int e = base + e0 + j;
            float* op = &out[(size_t)e * 8];
            #pragma unroll
            for (int o = 0; o < 8; ++o) op[o] = ((j == 0) ? po0[o] : po1[o]) + b2r[o];
        }
    }
}

// ---------------- K6: predicted_r0 gather ----------------
__global__ void k6_r0(const float* __restrict__ r_t, const float* __restrict__ delta,
                      const int* __restrict__ tn, float* __restrict__ out)
{
    int i = blockIdx.x * 256 + threadIdx.x;
    if (i < NTT * 3) {
        int t = i / 3, d = i - t * 3;
        int n = tn[t];
        out[i] = r_t[n * 3 + d] + delta[n * 3 + d];
    }
}

extern "C" void kernel_launch(void* const* d_in, const int* in_sizes, int n_in,
                              void* d_out, int out_size, void* d_ws, size_t ws_size,
                              hipStream_t stream)
{
    const float* h_final = (const float*)d_in[0];
    const float* e_final = (const float*)d_in[1];
    const float* r_t     = (const float*)d_in[2];
    const int*   tn      = (const int*)d_in[3];
    const int*   te      = (const int*)d_in[4];
    const int*   ei      = (const int*)d_in[5];
    const float* W_nsp   = (const float*)d_in[6];
    const float* b_nsp   = (const float*)d_in[7];
    const float* W_at1   = (const float*)d_in[8];
    const float* b_at1   = (const float*)d_in[9];
    const float* W_at2   = (const float*)d_in[10];
    const float* b_at2   = (const float*)d_in[11];
    const float* W_left  = (const float*)d_in[12];
    const float* b_left  = (const float*)d_in[13];
    const float* W_right = (const float*)d_in[14];
    const float* b_right = (const float*)d_in[15];
    const float* W_el1   = (const float*)d_in[16];
    const float* b_el1   = (const float*)d_in[17];
    const float* ln_g    = (const float*)d_in[18];
    const float* ln_b    = (const float*)d_in[19];
    const float* W_el2   = (const float*)d_in[20];
    const float* b_el2   = (const float*)d_in[21];
    const float* w_tp0   = (const float*)d_in[22];
    const float* w_tp1   = (const float*)d_in[23];
    const float* W_bh1   = (const float*)d_in[24];
    const float* b_bh1   = (const float*)d_in[25];
    const float* W_bh2   = (const float*)d_in[26];
    const float* b_bh2   = (const float*)d_in[27];

    float* ws    = (float*)d_ws;
    float* Wl    = ws;                    // 16384
    float* bl    = Wl + 16384;            // 128
    float* Wr    = bl + 128;              // 16384
    float* br    = Wr + 16384;            // 128
    float* hl    = br + 128;              // 6,400,000
    float* hr    = hl + 6400000;          // 6,400,000
    float* delta = hr + 6400000;          // 150,000
    float* tpb   = delta + 150000;        // 100,000

    float* out      = (float*)d_out;
    float* out_atom = out;                // 10000*32
    float* out_r0   = out + 320000;       // 10000*3
    float* out_bond = out + 350000;       // 100000*8

    k0_combine<<<64, 256, 0, stream>>>(W_nsp, b_nsp, W_left, b_left, W_right, b_right,
                                       Wl, bl, Wr, br);
    k1_nodeproj<<<256, 256, 0, stream>>>(h_final, Wl, bl, Wr, br, hl, hr);
    k2_atom<<<256, 256, 0, stream>>>(h_final, tn, W_nsp, b_nsp, W_at1, b_at1,
                                     W_at2, b_at2, out_atom);
    hipMemsetAsync(delta, 0, 150000 * sizeof(float), stream);
    k3_edge<<<256, 512, 0, stream>>>(e_final, ei, hl, hr, r_t, W_el1, b_el1,
                                     ln_g, ln_b, W_el2, b_el2, delta);
    k6_r0<<<(NTT * 3 + 255) / 256, 256, 0, stream>>>(r_t, delta, tn, out_r0);
    k4_tp<<<256, 256, 0, stream>>>(h_final, ei, te, w_tp0, w_tp1, tpb);
    k5_bond<<<256, 256, 0, stream>>>(e_final, te, tpb, W_bh1, b_bh1, W_bh2, b_bh2, out_bond);
}

// Round 2
// 1522.154 us; speedup vs baseline: 1.2956x; 1.2956x over previous
//
#include <hip/hip_runtime.h>
#include <math.h>

#define NN   50000
#define NE   500000
#define NTT  10000
#define ETT  100000
#define HF   320      // h_final row = 128 + 3*64
#define EFW  160      // e_final row = 64 + 3*32

typedef __attribute__((ext_vector_type(8))) short short8_t;
typedef __attribute__((ext_vector_type(4))) float f32x4;

__device__ __forceinline__ float silu_f(float x) { return x / (1.f + __expf(-x)); }

__device__ __forceinline__ short f2bf(float f) {
    unsigned u = __float_as_uint(f);
    unsigned r = (u + 0x7fffu + ((u >> 16) & 1u)) >> 16;
    return (short)r;
}

// ---------------- K0: fold W_nsp into W_left / W_right ----------------
__global__ __launch_bounds__(256) void k0_combine(
    const float* __restrict__ W_nsp, const float* __restrict__ b_nsp,
    const float* __restrict__ W_left, const float* __restrict__ b_left,
    const float* __restrict__ W_right, const float* __restrict__ b_right,
    float* __restrict__ Wl, float* __restrict__ bl,
    float* __restrict__ Wr, float* __restrict__ br)
{
    int idx = blockIdx.x * 256 + threadIdx.x;   // 0..16383
    int i = idx >> 7, j = idx & 127;
    float al = 0.f, ar = 0.f;
    for (int k = 0; k < 128; ++k) {
        float w = W_nsp[i * 128 + k];
        al = fmaf(w, W_left[k * 128 + j], al);
        ar = fmaf(w, W_right[k * 128 + j], ar);
    }
    Wl[idx] = al; Wr[idx] = ar;
    if (i == 0) {
        float cl = 0.f, cr = 0.f;
        for (int k = 0; k < 128; ++k) {
            float bn = b_nsp[k];
            cl = fmaf(bn, W_left[k * 128 + j], cl);
            cr = fmaf(bn, W_right[k * 128 + j], cr);
        }
        bl[j] = cl + b_left[j];
        br[j] = cr + b_right[j];
    }
}

// ---------------- K1: hl/hr for all nodes ----------------
__global__ __launch_bounds__(256) void k1_nodeproj(
    const float* __restrict__ h_final,
    const float* __restrict__ Wl, const float* __restrict__ bl,
    const float* __restrict__ Wr, const float* __restrict__ br,
    float* __restrict__ hl, float* __restrict__ hr)
{
    __shared__ float sWl[16384];
    __shared__ float sWr[16384];
    __shared__ float sx[8][128];
    const int tid = threadIdx.x;
    for (int i = tid; i < 16384; i += 256) { sWl[i] = Wl[i]; sWr[i] = Wr[i]; }
    const int j = tid & 127;
    const int sub = tid >> 7;
    const float blj = bl[j], brj = br[j];
    for (int base = blockIdx.x * 8; base < NN; base += gridDim.x * 8) {
        __syncthreads();
        #pragma unroll
        for (int t = tid; t < 1024; t += 256) {
            int n = t >> 7;
            sx[n][t & 127] = h_final[(size_t)(base + n) * HF + (t & 127)];
        }
        __syncthreads();
        const int n0 = sub * 4;
        float accl[4] = {0.f,0.f,0.f,0.f}, accr[4] = {0.f,0.f,0.f,0.f};
        for (int k = 0; k < 128; ++k) {
            float wl = sWl[k * 128 + j], wr = sWr[k * 128 + j];
            #pragma unroll
            for (int u = 0; u < 4; ++u) {
                float xv = sx[n0 + u][k];
                accl[u] = fmaf(xv, wl, accl[u]);
                accr[u] = fmaf(xv, wr, accr[u]);
            }
        }
        #pragma unroll
        for (int u = 0; u < 4; ++u) {
            size_t n = (size_t)(base + n0 + u);
            hl[n * 128 + j] = accl[u] + blj;
            hr[n * 128 + j] = accr[u] + brj;
        }
    }
}

// ---------------- K2: atom-type head ----------------
__global__ __launch_bounds__(256) void k2_atom(
    const float* __restrict__ h_final, const int* __restrict__ tn,
    const float* __restrict__ W_nsp, const float* __restrict__ b_nsp,
    const float* __restrict__ W_at1, const float* __restrict__ b_at1,
    const float* __restrict__ W_at2, const float* __restrict__ b_at2,
    float* __restrict__ out)
{
    __shared__ float sW0[16384], sW1[16384], sW2[4096];
    __shared__ float sx[2][128], ss[2][128], sa[2][128];
    const int tid = threadIdx.x;
    for (int i = tid; i < 16384; i += 256) { sW0[i] = W_nsp[i]; sW1[i] = W_at1[i]; }
    for (int i = tid; i < 4096; i += 256) sW2[i] = W_at2[i];
    const int j = tid & 127, sub = tid >> 7;
    const float bn = b_nsp[j], ba1 = b_at1[j];
    const float ba2 = (j < 32) ? b_at2[j] : 0.f;
    for (int base = blockIdx.x * 2; base < NTT; base += gridDim.x * 2) {
        __syncthreads();
        const int t = base + sub;
        const int node = tn[t];
        sx[sub][j] = h_final[(size_t)node * HF + j];
        __syncthreads();
        float acc = 0.f;
        for (int k = 0; k < 128; ++k) acc = fmaf(sx[sub][k], sW0[k * 128 + j], acc);
        ss[sub][j] = acc + bn;
        __syncthreads();
        acc = 0.f;
        for (int k = 0; k < 128; ++k) acc = fmaf(ss[sub][k], sW1[k * 128 + j], acc);
        sa[sub][j] = silu_f(acc + ba1);
        __syncthreads();
        if (j < 32) {
            float o = 0.f;
            for (int k = 0; k < 128; ++k) o = fmaf(sa[sub][k], sW2[k * 32 + j], o);
            out[(size_t)t * 32 + j] = o + ba2;
        }
    }
}

// ---------------- K3: edge MLP via MFMA + force accumulation ----------------
// tile = 64 edges x 128 outputs, K = 224 (64 e_scalar + 32 norms + 128 inter)
// 4 waves: wave w owns cols [w*32, w*32+32); all waves cover rows 0..63.
// B (W_el1) fragments live in registers across the tile loop.
#define KP3 232                      // padded LDS row stride (shorts)
#define NT3 ((NE + 63) / 64)

__global__ __launch_bounds__(256, 2) void k3_edge_mfma(
    const float* __restrict__ e_final, const int* __restrict__ edge_index,
    const float* __restrict__ hl, const float* __restrict__ hr,
    const float* __restrict__ r_t,
    const float* __restrict__ W_el1, const float* __restrict__ b_el1,
    const float* __restrict__ ln_g, const float* __restrict__ ln_b,
    const float* __restrict__ W_el2, const float* __restrict__ b_el2,
    float* __restrict__ delta)
{
    __shared__ __align__(16) char smem[64 * 132 * 4];   // 33792 B union
    short (*sx)[KP3] = (short(*)[KP3])smem;             // 64 x 232 shorts = 29696 B
    float (*sy)[132] = (float(*)[132])smem;             // 64 x 132 floats = 33792 B
    __shared__ float slng[128], slnb[128], sw2[128];

    const int tid  = threadIdx.x;
    const int w    = tid >> 6;       // wave 0..3
    const int lane = tid & 63;
    const int g    = lane >> 4;      // 0..3
    const int ln   = lane & 15;

    if (tid < 128) { slng[tid] = ln_g[tid]; slnb[tid] = ln_b[tid]; sw2[tid] = W_el2[tid]; }
    const float b2 = b_el2[0];

    // B fragments: B[k][n] = W_el1[k*128 + n]; lane holds k = k0*32 + g*8 + j, n = w*32 + nf*16 + ln
    short8_t bfr[7][2];
    #pragma unroll
    for (int k0 = 0; k0 < 7; ++k0) {
        #pragma unroll
        for (int nf = 0; nf < 2; ++nf) {
            short8_t bb;
            #pragma unroll
            for (int j = 0; j < 8; ++j)
                bb[j] = f2bf(W_el1[(k0 * 32 + g * 8 + j) * 128 + w * 32 + nf * 16 + ln]);
            bfr[k0][nf] = bb;
        }
    }
    const float bias0 = b_el1[w * 32 + ln];
    const float bias1 = b_el1[w * 32 + 16 + ln];

    const int cfix = tid & 127;      // inter staging column
    const int esub = tid >> 7;       // 0..1

    for (int tile = blockIdx.x; tile < NT3; tile += gridDim.x) {
        const int base = tile * 64;
        __syncthreads();             // protect previous tile's sy reads

        // ---- stage x (bf16) into sx ----
        // e_scalar: cols 0..63
        #pragma unroll
        for (int it = 0; it < 4; ++it) {
            int i = tid + it * 256;          // 0..1023
            int e = i >> 4, c4 = i & 15;
            int ge = base + e;
            float4 v = make_float4(0.f, 0.f, 0.f, 0.f);
            if (ge < NE) v = *(const float4*)&e_final[(size_t)ge * EFW + c4 * 4];
            short4 s4;
            s4.x = f2bf(v.x); s4.y = f2bf(v.y); s4.z = f2bf(v.z); s4.w = f2bf(v.w);
            *(short4*)&sx[e][c4 * 4] = s4;
        }
        // e_high norms: cols 64..95
        #pragma unroll
        for (int it = 0; it < 8; ++it) {
            int i = tid + it * 256;          // 0..2047
            int e = i >> 5, v = i & 31;
            int ge = base + e;
            float nv = 0.f;
            if (ge < NE) {
                const float* p = &e_final[(size_t)ge * EFW + 64 + v * 3];
                nv = sqrtf(p[0]*p[0] + p[1]*p[1] + p[2]*p[2]);
            }
            sx[e][64 + v] = f2bf(nv);
        }
        // inter: cols 96..223
        #pragma unroll
        for (int jj = 0; jj < 32; ++jj) {
            int e = esub + 2 * jj;
            int ge = base + e;
            float pv = 0.f;
            if (ge < NE) {
                int r  = edge_index[ge];
                int cl = edge_index[NE + ge];
                pv = hl[(size_t)r * 128 + cfix] * hr[(size_t)cl * 128 + cfix];
            }
            sx[e][96 + cfix] = f2bf(pv);
        }
        __syncthreads();

        // ---- MFMA: y[64][128] = x[64][224] @ W[224][128] ----
        f32x4 acc[4][2];
        #pragma unroll
        for (int mf = 0; mf < 4; ++mf)
            #pragma unroll
            for (int nf = 0; nf < 2; ++nf)
                acc[mf][nf] = (f32x4){0.f, 0.f, 0.f, 0.f};
        #pragma unroll
        for (int k0 = 0; k0 < 7; ++k0) {
            short8_t a[4];
            #pragma unroll
            for (int mf = 0; mf < 4; ++mf)
                a[mf] = *(const short8_t*)&sx[mf * 16 + ln][k0 * 32 + g * 8];
            #pragma unroll
            for (int mf = 0; mf < 4; ++mf)
                #pragma unroll
                for (int nf = 0; nf < 2; ++nf)
                    acc[mf][nf] = __builtin_amdgcn_mfma_f32_16x16x32_bf16(
                        a[mf], bfr[k0][nf], acc[mf][nf], 0, 0, 0);
        }
        __syncthreads();             // sx reads done before sy overwrite

        // ---- write y = acc + bias (D layout: col=ln, row=g*4+r within fragment) ----
        #pragma unroll
        for (int mf = 0; mf < 4; ++mf) {
            #pragma unroll
            for (int nf = 0; nf < 2; ++nf) {
                #pragma unroll
                for (int r = 0; r < 4; ++r)
                    sy[mf * 16 + g * 4 + r][w * 32 + nf * 16 + ln] =
                        acc[mf][nf][r] + (nf ? bias1 : bias0);
            }
        }
        __syncthreads();

        // ---- LayerNorm + silu + W_el2 dot + force ----
        {
            const int row = tid >> 2, q = tid & 3;
            float s = 0.f, qs = 0.f;
            #pragma unroll
            for (int i = 0; i < 8; ++i) {
                float4 v = *(const float4*)&sy[row][q * 32 + i * 4];
                s  += v.x + v.y + v.z + v.w;
                qs += v.x*v.x + v.y*v.y + v.z*v.z + v.w*v.w;
            }
            s += __shfl_xor(s, 1); qs += __shfl_xor(qs, 1);
            s += __shfl_xor(s, 2); qs += __shfl_xor(qs, 2);
            const float mu = s * (1.f / 128.f);
            const float iv = rsqrtf(qs * (1.f / 128.f) - mu * mu + 1e-5f);
            float p = 0.f;
            #pragma unroll
            for (int i = 0; i < 8; ++i) {
                int c = q * 32 + i * 4;
                float4 v  = *(const float4*)&sy[row][c];
                float4 gv = *(const float4*)&slng[c];
                float4 bv = *(const float4*)&slnb[c];
                float4 wv = *(const float4*)&sw2[c];
                p += silu_f((v.x - mu) * iv * gv.x + bv.x) * wv.x;
                p += silu_f((v.y - mu) * iv * gv.y + bv.y) * wv.y;
                p += silu_f((v.z - mu) * iv * gv.z + bv.z) * wv.z;
                p += silu_f((v.w - mu) * iv * gv.w + bv.w) * wv.w;
            }
            p += __shfl_xor(p, 1); p += __shfl_xor(p, 2);
            const int ge = base + row;
            if (q == 0 && ge < NE) {
                float we = p + b2;
                int r  = edge_index[ge];
                int cl = edge_index[NE + ge];
                float rx = r_t[r*3+0] - r_t[cl*3+0];
                float ry = r_t[r*3+1] - r_t[cl*3+1];
                float rz = r_t[r*3+2] - r_t[cl*3+2];
                float dist = sqrtf(rx*rx + ry*ry + rz*rz) + 1e-8f;
                float f = we / (dist * (dist + 1.f));
                atomicAdd(&delta[r*3+0], f*rx);
                atomicAdd(&delta[r*3+1], f*ry);
                atomicAdd(&delta[r*3+2], f*rz);
            }
        }
    }
}

// ---------------- K4: tensor-product scalar per target edge ----------------
__global__ __launch_bounds__(256) void k4_tp(
    const float* __restrict__ h_final, const int* __restrict__ edge_index,
    const int* __restrict__ te,
    const float* __restrict__ w_tp0, const float* __restrict__ w_tp1,
    float* __restrict__ tp)
{
    __shared__ float sW0[128 * 129];     // padded: bank-conflict-free
    __shared__ float sW1[64 * 65];
    __shared__ float ssy[4][128];
    __shared__ float svy[4][64][4];
    const int tid = threadIdx.x;
    for (int i = tid; i < 128 * 128; i += 256) sW0[(i >> 7) * 129 + (i & 127)] = w_tp0[i];
    for (int i = tid; i < 64 * 64; i += 256)  sW1[(i >> 6) * 65 + (i & 63)] = w_tp1[i];
    const int w = tid >> 6, l = tid & 63;
    for (int base = blockIdx.x * 4; base < ETT; base += gridDim.x * 4) {
        __syncthreads();
        const int e = base + w;
        const bool act = (e < ETT);
        int r2 = 0;
        if (act) {
            int ge = te[e];
            r2 = edge_index[ge];
            int c2 = edge_index[NE + ge];
            const float* hc = &h_final[(size_t)c2 * HF];
            ssy[w][l] = hc[l];
            ssy[w][l + 64] = hc[l + 64];
            #pragma unroll
            for (int mm = 0; mm < 3; ++mm) {
                int m = l + mm * 64;
                svy[w][m / 3][m % 3] = hc[128 + m];
            }
        }
        __syncthreads();
        float res = 0.f;
        if (act) {
            const float* ha = &h_final[(size_t)r2 * HF];
            const float sx1 = ha[l], sx2 = ha[l + 64];
            float a1 = 0.f, a2 = 0.f;
            for (int jj = 0; jj < 128; ++jj) {
                float syv = ssy[w][jj];
                a1 = fmaf(sW0[l * 129 + jj], syv, a1);
                a2 = fmaf(sW0[(l + 64) * 129 + jj], syv, a2);
            }
            float sres = sx1 * a1 + sx2 * a2;
            const float vx0 = ha[128 + l*3 + 0];
            const float vx1 = ha[128 + l*3 + 1];
            const float vx2 = ha[128 + l*3 + 2];
            float t0 = 0.f, t1 = 0.f, t2 = 0.f;
            for (int jj = 0; jj < 64; ++jj) {
                float wv = sW1[l * 65 + jj];
                t0 = fmaf(wv, svy[w][jj][0], t0);
                t1 = fmaf(wv, svy[w][jj][1], t1);
                t2 = fmaf(wv, svy[w][jj][2], t2);
            }
            float vres = vx0*t0 + vx1*t1 + vx2*t2;
            res = sres * (1.f/128.f) + vres * (1.f/110.85125168440814f); // 64*sqrt(3)
        }
        #pragma unroll
        for (int m = 32; m >= 1; m >>= 1) res += __shfl_xor(res, m);
        if (act && l == 0) tp[e] = res;
    }
}

// ---------------- K5: bond head ----------------
__global__ __launch_bounds__(256) void k5_bond(
    const float* __restrict__ e_final, const int* __restrict__ te,
    const float* __restrict__ tp,
    const float* __restrict__ W_bh1, const float* __restrict__ b_bh1,
    const float* __restrict__ W_bh2, const float* __restrict__ b_bh2,
    float* __restrict__ out)
{
    __shared__ float sW[164 * 128];      // rows 161..163 zeroed
    __shared__ float sx[16][164];        // [161..163] zeroed
    const int tid = threadIdx.x;
    for (int i = tid; i < 161 * 128; i += 256) sW[i] = W_bh1[i];
    for (int i = tid; i < 3 * 128; i += 256) sW[161 * 128 + i] = 0.f;
    for (int i = tid; i < 16 * 3; i += 256) sx[i / 3][161 + (i % 3)] = 0.f;
    const int j = tid & 31, g = tid >> 5;
    float bj[4];
    { float4 tv = *(const float4*)&b_bh1[4 * j]; bj[0]=tv.x; bj[1]=tv.y; bj[2]=tv.z; bj[3]=tv.w; }
    float w2r[4][8], b2r[8];
    #pragma unroll
    for (int c = 0; c < 4; ++c)
        #pragma unroll
        for (int o = 0; o < 8; ++o) w2r[c][o] = W_bh2[(4*j + c) * 8 + o];
    #pragma unroll
    for (int o = 0; o < 8; ++o) b2r[o] = b_bh2[o];
    for (int base = blockIdx.x * 16; base < ETT; base += gridDim.x * 16) {
        __syncthreads();
        for (int idx = tid; idx < 16 * 161; idx += 256) {
            int e = idx / 161, k = idx - e * 161;
            sx[e][k] = (k == 0) ? tp[base + e]
                                : e_final[(size_t)te[base + e] * EFW + (k - 1)];
        }
        __syncthreads();
        const int e0 = g * 2;
        float acc0[4] = {0,0,0,0}, acc1[4] = {0,0,0,0};
        #pragma unroll 4
        for (int k = 0; k < 164; k += 4) {
            float4 xa = *(const float4*)&sx[e0][k];
            float4 xb = *(const float4*)&sx[e0 + 1][k];
            const float xav[4] = {xa.x, xa.y, xa.z, xa.w};
            const float xbv[4] = {xb.x, xb.y, xb.z, xb.w};
            #pragma unroll
            for (int u = 0; u < 4; ++u) {
                float4 wv = *(const float4*)&sW[(k + u) * 128 + 4 * j];
                acc0[0] = fmaf(xav[u], wv.x, acc0[0]);
                acc0[1] = fmaf(xav[u], wv.y, acc0[1]);
                acc0[2] = fmaf(xav[u], wv.z, acc0[2]);
                acc0[3] = fmaf(xav[u], wv.w, acc0[3]);
                acc1[0] = fmaf(xbv[u], wv.x, acc1[0]);
                acc1[1] = fmaf(xbv[u], wv.y, acc1[1]);
                acc1[2] = fmaf(xbv[u], wv.z, acc1[2]);
                acc1[3] = fmaf(xbv[u], wv.w, acc1[3]);
            }
        }
        float po0[8] = {0,0,0,0,0,0,0,0}, po1[8] = {0,0,0,0,0,0,0,0};
        #pragma unroll
        for (int c = 0; c < 4; ++c) {
            float a0 = silu_f(acc0[c] + bj[c]);
            float a1 = silu_f(acc1[c] + bj[c]);
            #pragma unroll
            for (int o = 0; o < 8; ++o) {
                po0[o] = fmaf(a0, w2r[c][o], po0[o]);
                po1[o] = fmaf(a1, w2r[c][o], po1[o]);
            }
        }
        #pragma unroll
        for (int m = 16; m >= 1; m >>= 1) {
            #pragma unroll
            for (int o = 0; o < 8; ++o) {
                po0[o] += __shfl_xor(po0[o], m);
                po1[o] += __shfl_xor(po1[o], m);
            }
        }
        if (j < 2) {
            int e = base + e0 + j;
            float* op = &out[(size_t)e * 8];
            #pragma unroll
            for (int o = 0; o < 8; ++o) op[o] = ((j == 0) ? po0[o] : po1[o]) + b2r[o];
        }
    }
}

// ---------------- K6: predicted_r0 gather ----------------
__global__ void k6_r0(const float* __restrict__ r_t, const float* __restrict__ delta,
                      const int* __restrict__ tn, float* __restrict__ out)
{
    int i = blockIdx.x * 256 + threadIdx.x;
    if (i < NTT * 3) {
        int t = i / 3, d = i - t * 3;
        int n = tn[t];
        out[i] = r_t[n * 3 + d] + delta[n * 3 + d];
    }
}

extern "C" void kernel_launch(void* const* d_in, const int* in_sizes, int n_in,
                              void* d_out, int out_size, void* d_ws, size_t ws_size,
                              hipStream_t stream)
{
    const float* h_final = (const float*)d_in[0];
    const float* e_final = (const float*)d_in[1];
    const float* r_t     = (const float*)d_in[2];
    const int*   tn      = (const int*)d_in[3];
    const int*   te      = (const int*)d_in[4];
    const int*   ei      = (const int*)d_in[5];
    const float* W_nsp   = (const float*)d_in[6];
    const float* b_nsp   = (const float*)d_in[7];
    const float* W_at1   = (const float*)d_in[8];
    const float* b_at1   = (const float*)d_in[9];
    const float* W_at2   = (const float*)d_in[10];
    const float* b_at2   = (const float*)d_in[11];
    const float* W_left  = (const float*)d_in[12];
    const float* b_left  = (const float*)d_in[13];
    const float* W_right = (const float*)d_in[14];
    const float* b_right = (const float*)d_in[15];
    const float* W_el1   = (const float*)d_in[16];
    const float* b_el1   = (const float*)d_in[17];
    const float* ln_g    = (const float*)d_in[18];
    const float* ln_b    = (const float*)d_in[19];
    const float* W_el2   = (const float*)d_in[20];
    const float* b_el2   = (const float*)d_in[21];
    const float* w_tp0   = (const float*)d_in[22];
    const float* w_tp1   = (const float*)d_in[23];
    const float* W_bh1   = (const float*)d_in[24];
    const float* b_bh1   = (const float*)d_in[25];
    const float* W_bh2   = (const float*)d_in[26];
    const float* b_bh2   = (const float*)d_in[27];

    float* ws    = (float*)d_ws;
    float* Wl    = ws;                    // 16384
    float* bl    = Wl + 16384;            // 128
    float* Wr    = bl + 128;              // 16384
    float* br    = Wr + 16384;            // 128
    float* hl    = br + 128;              // 6,400,000
    float* hr    = hl + 6400000;          // 6,400,000
    float* delta = hr + 6400000;          // 150,000
    float* tpb   = delta + 150000;        // 100,000

    float* out      = (float*)d_out;
    float* out_atom = out;                // 10000*32
    float* out_r0   = out + 320000;       // 10000*3
    float* out_bond = out + 350000;       // 100000*8

    k0_combine<<<64, 256, 0, stream>>>(W_nsp, b_nsp, W_left, b_left, W_right, b_right,
                                       Wl, bl, Wr, br);
    k1_nodeproj<<<256, 256, 0, stream>>>(h_final, Wl, bl, Wr, br, hl, hr);
    k2_atom<<<256, 256, 0, stream>>>(h_final, tn, W_nsp, b_nsp, W_at1, b_at1,
                                     W_at2, b_at2, out_atom);
    hipMemsetAsync(delta, 0, 150000 * sizeof(float), stream);
    k3_edge_mfma<<<1024, 256, 0, stream>>>(e_final, ei, hl, hr, r_t, W_el1, b_el1,
                                           ln_g, ln_b, W_el2, b_el2, delta);
    k6_r0<<<(NTT * 3 + 255) / 256, 256, 0, stream>>>(r_t, delta, tn, out_r0);
    k4_tp<<<256, 256, 0, stream>>>(h_final, ei, te, w_tp0, w_tp1, tpb);
    k5_bond<<<256, 256, 0, stream>>>(e_final, te, tpb, W_bh1, b_bh1, W_bh2, b_bh2, out_bond);
}

// Round 3
// 532.629 us; speedup vs baseline: 3.7026x; 2.8578x over previous
//
#include <hip/hip_runtime.h>
#include <math.h>

#define NN   50000
#define NE   500000
#define NTT  10000
#define ETT  100000
#define HF   320      // h_final row = 128 + 3*64
#define EFW  160      // e_final row = 64 + 3*32

typedef __attribute__((ext_vector_type(8))) short short8_t;
typedef __attribute__((ext_vector_type(4))) float f32x4;

__device__ __forceinline__ float silu_f(float x) { return x / (1.f + __expf(-x)); }

__device__ __forceinline__ short f2bf(float f) {
    unsigned u = __float_as_uint(f);
    unsigned r = (u + 0x7fffu + ((u >> 16) & 1u)) >> 16;
    return (short)r;
}
__device__ __forceinline__ float bf2f(short s) {
    return __uint_as_float(((unsigned)(unsigned short)s) << 16);
}

// ---------------- K0: fold W_nsp into W_left / W_right ----------------
__global__ __launch_bounds__(256) void k0_combine(
    const float* __restrict__ W_nsp, const float* __restrict__ b_nsp,
    const float* __restrict__ W_left, const float* __restrict__ b_left,
    const float* __restrict__ W_right, const float* __restrict__ b_right,
    float* __restrict__ Wl, float* __restrict__ bl,
    float* __restrict__ Wr, float* __restrict__ br)
{
    int idx = blockIdx.x * 256 + threadIdx.x;   // 0..16383
    int i = idx >> 7, j = idx & 127;
    float al = 0.f, ar = 0.f;
    for (int k = 0; k < 128; ++k) {
        float w = W_nsp[i * 128 + k];
        al = fmaf(w, W_left[k * 128 + j], al);
        ar = fmaf(w, W_right[k * 128 + j], ar);
    }
    Wl[idx] = al; Wr[idx] = ar;
    if (i == 0) {
        float cl = 0.f, cr = 0.f;
        for (int k = 0; k < 128; ++k) {
            float bn = b_nsp[k];
            cl = fmaf(bn, W_left[k * 128 + j], cl);
            cr = fmaf(bn, W_right[k * 128 + j], cr);
        }
        bl[j] = cl + b_left[j];
        br[j] = cr + b_right[j];
    }
}

// ---------------- K1: hl/hr via MFMA, bf16 outputs ----------------
#define KP1 136
__global__ __launch_bounds__(256) void k1_mfma(
    const float* __restrict__ h_final,
    const float* __restrict__ Wl, const float* __restrict__ bl,
    const float* __restrict__ Wr, const float* __restrict__ br,
    short* __restrict__ hlb, short* __restrict__ hrb)
{
    __shared__ __align__(16) short sx[64][KP1];
    const int tid = threadIdx.x;
    const int w = tid >> 6, lane = tid & 63, g = lane >> 4, ln = lane & 15;

    // B frags: col = w*64 + nf*16 + ln; k = k0*32 + g*8 + j
    short8_t bfr[4][4];
    float bias[4];
    #pragma unroll
    for (int nf = 0; nf < 4; ++nf) {
        int col = w * 64 + nf * 16 + ln;
        const float* Wsrc = (col < 128) ? Wl : Wr;
        int cc = col & 127;
        bias[nf] = (col < 128) ? bl[cc] : br[cc];
        #pragma unroll
        for (int k0 = 0; k0 < 4; ++k0) {
            short8_t bb;
            #pragma unroll
            for (int j = 0; j < 8; ++j)
                bb[j] = f2bf(Wsrc[(k0 * 32 + g * 8 + j) * 128 + cc]);
            bfr[k0][nf] = bb;
        }
    }

    const int base = blockIdx.x * 64;
    {
        const int e = tid >> 2, q = tid & 3;
        const int n = base + e;
        #pragma unroll
        for (int i = 0; i < 8; ++i) {
            float4 v = make_float4(0.f, 0.f, 0.f, 0.f);
            if (n < NN) v = *(const float4*)&h_final[(size_t)n * HF + q * 32 + i * 4];
            short4 s4; s4.x = f2bf(v.x); s4.y = f2bf(v.y); s4.z = f2bf(v.z); s4.w = f2bf(v.w);
            *(short4*)&sx[e][q * 32 + i * 4] = s4;
        }
    }
    __syncthreads();
    f32x4 acc[4][4];
    #pragma unroll
    for (int mf = 0; mf < 4; ++mf)
        #pragma unroll
        for (int nf = 0; nf < 4; ++nf)
            acc[mf][nf] = (f32x4){0.f, 0.f, 0.f, 0.f};
    #pragma unroll
    for (int k0 = 0; k0 < 4; ++k0) {
        short8_t a[4];
        #pragma unroll
        for (int mf = 0; mf < 4; ++mf)
            a[mf] = *(const short8_t*)&sx[mf * 16 + ln][k0 * 32 + g * 8];
        #pragma unroll
        for (int mf = 0; mf < 4; ++mf)
            #pragma unroll
            for (int nf = 0; nf < 4; ++nf)
                acc[mf][nf] = __builtin_amdgcn_mfma_f32_16x16x32_bf16(
                    a[mf], bfr[k0][nf], acc[mf][nf], 0, 0, 0);
    }
    #pragma unroll
    for (int mf = 0; mf < 4; ++mf)
        #pragma unroll
        for (int nf = 0; nf < 4; ++nf) {
            int col = w * 64 + nf * 16 + ln;
            #pragma unroll
            for (int r = 0; r < 4; ++r) {
                int n = base + mf * 16 + g * 4 + r;
                if (n < NN) {
                    short v = f2bf(acc[mf][nf][r] + bias[nf]);
                    if (col < 128) hlb[(size_t)n * 128 + col] = v;
                    else           hrb[(size_t)n * 128 + col - 128] = v;
                }
            }
        }
}

// ---------------- K2: atom-type head ----------------
__global__ __launch_bounds__(256) void k2_atom(
    const float* __restrict__ h_final, const int* __restrict__ tn,
    const float* __restrict__ W_nsp, const float* __restrict__ b_nsp,
    const float* __restrict__ W_at1, const float* __restrict__ b_at1,
    const float* __restrict__ W_at2, const float* __restrict__ b_at2,
    float* __restrict__ out)
{
    __shared__ float sW0[16384], sW1[16384], sW2[4096];
    __shared__ float sx[2][128], ss[2][128], sa[2][128];
    const int tid = threadIdx.x;
    for (int i = tid; i < 16384; i += 256) { sW0[i] = W_nsp[i]; sW1[i] = W_at1[i]; }
    for (int i = tid; i < 4096; i += 256) sW2[i] = W_at2[i];
    const int j = tid & 127, sub = tid >> 7;
    const float bn = b_nsp[j], ba1 = b_at1[j];
    const float ba2 = (j < 32) ? b_at2[j] : 0.f;
    for (int base = blockIdx.x * 2; base < NTT; base += gridDim.x * 2) {
        __syncthreads();
        const int t = base + sub;
        const int node = tn[t];
        sx[sub][j] = h_final[(size_t)node * HF + j];
        __syncthreads();
        float acc = 0.f;
        for (int k = 0; k < 128; ++k) acc = fmaf(sx[sub][k], sW0[k * 128 + j], acc);
        ss[sub][j] = acc + bn;
        __syncthreads();
        acc = 0.f;
        for (int k = 0; k < 128; ++k) acc = fmaf(ss[sub][k], sW1[k * 128 + j], acc);
        sa[sub][j] = silu_f(acc + ba1);
        __syncthreads();
        if (j < 32) {
            float o = 0.f;
            for (int k = 0; k < 128; ++k) o = fmaf(sa[sub][k], sW2[k * 32 + j], o);
            out[(size_t)t * 32 + j] = o + ba2;
        }
    }
}

// ---------------- K3: edge MLP via MFMA + force accumulation ----------------
#define KP3 264
#define NT3 ((NE + 63) / 64)

__global__ __launch_bounds__(256) void k3_edge_mfma(
    const float* __restrict__ e_final, const int* __restrict__ edge_index,
    const short* __restrict__ hlb, const short* __restrict__ hrb,
    const float* __restrict__ r_t,
    const float* __restrict__ W_el1, const float* __restrict__ b_el1,
    const float* __restrict__ ln_g, const float* __restrict__ ln_b,
    const float* __restrict__ W_el2, const float* __restrict__ b_el2,
    float* __restrict__ delta)
{
    __shared__ __align__(16) char smem[64 * 134 * 4];   // 34304 B union
    short (*sx)[KP3] = (short(*)[KP3])smem;             // 64 x 264 shorts = 33792 B
    float (*sy)[134] = (float(*)[134])smem;             // 64 x 134 floats = 34304 B
    __shared__ float slng[128], slnb[128], sw2[128];

    const int tid  = threadIdx.x;
    const int w    = tid >> 6;
    const int lane = tid & 63;
    const int g    = lane >> 4;
    const int ln   = lane & 15;

    if (tid < 128) { slng[tid] = ln_g[tid]; slnb[tid] = ln_b[tid]; sw2[tid] = W_el2[tid]; }
    const float b2 = b_el2[0];

    short8_t bfr[7][2];
    #pragma unroll
    for (int k0 = 0; k0 < 7; ++k0) {
        #pragma unroll
        for (int nf = 0; nf < 2; ++nf) {
            short8_t bb;
            #pragma unroll
            for (int j = 0; j < 8; ++j)
                bb[j] = f2bf(W_el1[(k0 * 32 + g * 8 + j) * 128 + w * 32 + nf * 16 + ln]);
            bfr[k0][nf] = bb;
        }
    }
    const float bias0 = b_el1[w * 32 + ln];
    const float bias1 = b_el1[w * 32 + 16 + ln];

    const int es = tid >> 2, qs = tid & 3;   // staging: 4 threads per edge

    for (int tile = blockIdx.x; tile < NT3; tile += gridDim.x) {
        const int base = tile * 64;
        __syncthreads();             // protect previous tile's sy reads

        // ---- stage x (bf16) into sx, vectorized ----
        {
            const int ge = base + es;
            const bool valid = (ge < NE);
            int r = 0, cl = 0;
            if (valid) { r = edge_index[ge]; cl = edge_index[NE + ge]; }
            // e_scalar: cols qs*16 .. +16
            #pragma unroll
            for (int i = 0; i < 4; ++i) {
                float4 v = make_float4(0.f, 0.f, 0.f, 0.f);
                if (valid) v = *(const float4*)&e_final[(size_t)ge * EFW + qs * 16 + i * 4];
                short4 s4; s4.x = f2bf(v.x); s4.y = f2bf(v.y); s4.z = f2bf(v.z); s4.w = f2bf(v.w);
                *(short4*)&sx[es][qs * 16 + i * 4] = s4;
            }
            // norms: vecs qs*8 .. +8  -> cols 64+qs*8
            {
                float f[24];
                #pragma unroll
                for (int i = 0; i < 6; ++i) {
                    float4 v = make_float4(0.f, 0.f, 0.f, 0.f);
                    if (valid) v = *(const float4*)&e_final[(size_t)ge * EFW + 64 + qs * 24 + i * 4];
                    f[4*i] = v.x; f[4*i+1] = v.y; f[4*i+2] = v.z; f[4*i+3] = v.w;
                }
                short4 n0, n1;
                n0.x = f2bf(sqrtf(f[0]*f[0]   + f[1]*f[1]   + f[2]*f[2]));
                n0.y = f2bf(sqrtf(f[3]*f[3]   + f[4]*f[4]   + f[5]*f[5]));
                n0.z = f2bf(sqrtf(f[6]*f[6]   + f[7]*f[7]   + f[8]*f[8]));
                n0.w = f2bf(sqrtf(f[9]*f[9]   + f[10]*f[10] + f[11]*f[11]));
                n1.x = f2bf(sqrtf(f[12]*f[12] + f[13]*f[13] + f[14]*f[14]));
                n1.y = f2bf(sqrtf(f[15]*f[15] + f[16]*f[16] + f[17]*f[17]));
                n1.z = f2bf(sqrtf(f[18]*f[18] + f[19]*f[19] + f[20]*f[20]));
                n1.w = f2bf(sqrtf(f[21]*f[21] + f[22]*f[22] + f[23]*f[23]));
                *(short4*)&sx[es][64 + qs * 8]     = n0;
                *(short4*)&sx[es][64 + qs * 8 + 4] = n1;
            }
            // inter: cols 96+qs*32 .. +32
            #pragma unroll
            for (int i = 0; i < 4; ++i) {
                short8_t hv, rv, pr;
                if (valid) {
                    hv = *(const short8_t*)&hlb[(size_t)r  * 128 + qs * 32 + i * 8];
                    rv = *(const short8_t*)&hrb[(size_t)cl * 128 + qs * 32 + i * 8];
                } else {
                    #pragma unroll
                    for (int jj = 0; jj < 8; ++jj) { hv[jj] = 0; rv[jj] = 0; }
                }
                #pragma unroll
                for (int jj = 0; jj < 8; ++jj)
                    pr[jj] = f2bf(bf2f(hv[jj]) * bf2f(rv[jj]));
                *(short8_t*)&sx[es][96 + qs * 32 + i * 8] = pr;
            }
        }
        __syncthreads();

        // ---- MFMA: y[64][128] = x[64][224] @ W[224][128] ----
        f32x4 acc[4][2];
        #pragma unroll
        for (int mf = 0; mf < 4; ++mf)
            #pragma unroll
            for (int nf = 0; nf < 2; ++nf)
                acc[mf][nf] = (f32x4){0.f, 0.f, 0.f, 0.f};
        #pragma unroll
        for (int k0 = 0; k0 < 7; ++k0) {
            short8_t a[4];
            #pragma unroll
            for (int mf = 0; mf < 4; ++mf)
                a[mf] = *(const short8_t*)&sx[mf * 16 + ln][k0 * 32 + g * 8];
            #pragma unroll
            for (int mf = 0; mf < 4; ++mf)
                #pragma unroll
                for (int nf = 0; nf < 2; ++nf)
                    acc[mf][nf] = __builtin_amdgcn_mfma_f32_16x16x32_bf16(
                        a[mf], bfr[k0][nf], acc[mf][nf], 0, 0, 0);
        }
        __syncthreads();             // sx reads done before sy overwrite

        #pragma unroll
        for (int mf = 0; mf < 4; ++mf)
            #pragma unroll
            for (int nf = 0; nf < 2; ++nf)
                #pragma unroll
                for (int r = 0; r < 4; ++r)
                    sy[mf * 16 + g * 4 + r][w * 32 + nf * 16 + ln] =
                        acc[mf][nf][r] + (nf ? bias1 : bias0);
        __syncthreads();

        // ---- LayerNorm + silu + W_el2 dot + force ----
        {
            const int row = tid >> 2, q2 = tid & 3;
            float s = 0.f, qsum = 0.f;
            #pragma unroll
            for (int i = 0; i < 16; ++i) {
                float2 v = *(const float2*)&sy[row][q2 * 32 + i * 2];
                s += v.x + v.y;
                qsum += v.x * v.x + v.y * v.y;
            }
            s += __shfl_xor(s, 1); qsum += __shfl_xor(qsum, 1);
            s += __shfl_xor(s, 2); qsum += __shfl_xor(qsum, 2);
            const float mu = s * (1.f / 128.f);
            const float iv = rsqrtf(qsum * (1.f / 128.f) - mu * mu + 1e-5f);
            float p = 0.f;
            #pragma unroll
            for (int i = 0; i < 16; ++i) {
                int c = q2 * 32 + i * 2;
                float2 v  = *(const float2*)&sy[row][c];
                float2 gv = *(const float2*)&slng[c];
                float2 bv = *(const float2*)&slnb[c];
                float2 wv = *(const float2*)&sw2[c];
                p += silu_f((v.x - mu) * iv * gv.x + bv.x) * wv.x;
                p += silu_f((v.y - mu) * iv * gv.y + bv.y) * wv.y;
            }
            p += __shfl_xor(p, 1); p += __shfl_xor(p, 2);
            const int ge = base + row;
            if (q2 == 0 && ge < NE) {
                float we = p + b2;
                int r  = edge_index[ge];
                int cl = edge_index[NE + ge];
                float rx = r_t[r*3+0] - r_t[cl*3+0];
                float ry = r_t[r*3+1] - r_t[cl*3+1];
                float rz = r_t[r*3+2] - r_t[cl*3+2];
                float dist = sqrtf(rx*rx + ry*ry + rz*rz) + 1e-8f;
                float f = we / (dist * (dist + 1.f));
                atomicAdd(&delta[r*3+0], f*rx);
                atomicAdd(&delta[r*3+1], f*ry);
                atomicAdd(&delta[r*3+2], f*rz);
            }
        }
    }
}

// ---------------- K4a: G = H_s @ w_tp0 (bf16 out) ----------------
__global__ __launch_bounds__(256) void k4a_g(
    const float* __restrict__ h_final, const float* __restrict__ w_tp0,
    short* __restrict__ Gb)
{
    __shared__ __align__(16) short sx[64][KP1];
    const int tid = threadIdx.x;
    const int w = tid >> 6, lane = tid & 63, g = lane >> 4, ln = lane & 15;

    short8_t bfr[4][2];
    #pragma unroll
    for (int k0 = 0; k0 < 4; ++k0)
        #pragma unroll
        for (int nf = 0; nf < 2; ++nf) {
            short8_t bb;
            #pragma unroll
            for (int j = 0; j < 8; ++j)
                bb[j] = f2bf(w_tp0[(k0 * 32 + g * 8 + j) * 128 + w * 32 + nf * 16 + ln]);
            bfr[k0][nf] = bb;
        }

    const int base = blockIdx.x * 64;
    {
        const int e = tid >> 2, q = tid & 3;
        const int n = base + e;
        #pragma unroll
        for (int i = 0; i < 8; ++i) {
            float4 v = make_float4(0.f, 0.f, 0.f, 0.f);
            if (n < NN) v = *(const float4*)&h_final[(size_t)n * HF + q * 32 + i * 4];
            short4 s4; s4.x = f2bf(v.x); s4.y = f2bf(v.y); s4.z = f2bf(v.z); s4.w = f2bf(v.w);
            *(short4*)&sx[e][q * 32 + i * 4] = s4;
        }
    }
    __syncthreads();
    f32x4 acc[4][2];
    #pragma unroll
    for (int mf = 0; mf < 4; ++mf)
        #pragma unroll
        for (int nf = 0; nf < 2; ++nf)
            acc[mf][nf] = (f32x4){0.f, 0.f, 0.f, 0.f};
    #pragma unroll
    for (int k0 = 0; k0 < 4; ++k0) {
        short8_t a[4];
        #pragma unroll
        for (int mf = 0; mf < 4; ++mf)
            a[mf] = *(const short8_t*)&sx[mf * 16 + ln][k0 * 32 + g * 8];
        #pragma unroll
        for (int mf = 0; mf < 4; ++mf)
            #pragma unroll
            for (int nf = 0; nf < 2; ++nf)
                acc[mf][nf] = __builtin_amdgcn_mfma_f32_16x16x32_bf16(
                    a[mf], bfr[k0][nf], acc[mf][nf], 0, 0, 0);
    }
    #pragma unroll
    for (int mf = 0; mf < 4; ++mf)
        #pragma unroll
        for (int nf = 0; nf < 2; ++nf) {
            int col = w * 32 + nf * 16 + ln;
            #pragma unroll
            for (int r = 0; r < 4; ++r) {
                int n = base + mf * 16 + g * 4 + r;
                if (n < NN) Gb[(size_t)n * 128 + col] = f2bf(acc[mf][nf][r]);
            }
        }
}

// ---------------- K4b: Gv[n] = w_tp1 @ V_n (bf16 out) ----------------
__global__ __launch_bounds__(256) void k4b_gv(
    const float* __restrict__ h_final, const float* __restrict__ w_tp1,
    short* __restrict__ Gvb)
{
    __shared__ float sW1T[64 * 65];
    __shared__ float sv[4][192];
    const int tid = threadIdx.x, w = tid >> 6, lane = tid & 63;
    for (int idx = tid; idx < 4096; idx += 256) {
        int i = idx >> 6, j = idx & 63;
        sW1T[j * 65 + i] = w_tp1[idx];
    }
    for (int base = blockIdx.x * 4; base < NN; base += gridDim.x * 4) {
        __syncthreads();
        if (tid < 192) {
            int nd = tid / 48, c4 = tid % 48;
            int n = base + nd;
            float4 v = make_float4(0.f, 0.f, 0.f, 0.f);
            if (n < NN) v = *(const float4*)&h_final[(size_t)n * HF + 128 + c4 * 4];
            *(float4*)&sv[nd][c4 * 4] = v;
        }
        __syncthreads();
        int n = base + w;
        if (n < NN) {
            float a0 = 0.f, a1 = 0.f, a2 = 0.f;
            for (int j = 0; j < 64; ++j) {
                float wv = sW1T[j * 65 + lane];
                a0 = fmaf(wv, sv[w][3 * j],     a0);
                a1 = fmaf(wv, sv[w][3 * j + 1], a1);
                a2 = fmaf(wv, sv[w][3 * j + 2], a2);
            }
            short* gp = &Gvb[(size_t)n * 192 + lane * 3];
            gp[0] = f2bf(a0); gp[1] = f2bf(a1); gp[2] = f2bf(a2);
        }
    }
}

// ---------------- K4c: tp per target edge via two dots ----------------
__global__ __launch_bounds__(256) void k4c_dot(
    const float* __restrict__ h_final, const int* __restrict__ edge_index,
    const int* __restrict__ te,
    const short* __restrict__ Gb, const short* __restrict__ Gvb,
    float* __restrict__ tp)
{
    const int tid = threadIdx.x;
    const int e = blockIdx.x * 32 + (tid >> 3);
    const int sub = tid & 7;
    float s1 = 0.f, s2 = 0.f;
    if (e < ETT) {
        int gid = te[e];
        int r2 = edge_index[gid], c2 = edge_index[NE + gid];
        #pragma unroll
        for (int i = 0; i < 2; ++i) {
            short8_t gv = *(const short8_t*)&Gb[(size_t)r2 * 128 + sub * 16 + i * 8];
            float4 h0 = *(const float4*)&h_final[(size_t)c2 * HF + sub * 16 + i * 8];
            float4 h1 = *(const float4*)&h_final[(size_t)c2 * HF + sub * 16 + i * 8 + 4];
            s1 += bf2f(gv[0])*h0.x + bf2f(gv[1])*h0.y + bf2f(gv[2])*h0.z + bf2f(gv[3])*h0.w
                + bf2f(gv[4])*h1.x + bf2f(gv[5])*h1.y + bf2f(gv[6])*h1.z + bf2f(gv[7])*h1.w;
        }
        #pragma unroll
        for (int i = 0; i < 3; ++i) {
            short8_t gv = *(const short8_t*)&Gvb[(size_t)c2 * 192 + sub * 24 + i * 8];
            float4 h0 = *(const float4*)&h_final[(size_t)r2 * HF + 128 + sub * 24 + i * 8];
            float4 h1 = *(const float4*)&h_final[(size_t)r2 * HF + 128 + sub * 24 + i * 8 + 4];
            s2 += bf2f(gv[0])*h0.x + bf2f(gv[1])*h0.y + bf2f(gv[2])*h0.z + bf2f(gv[3])*h0.w
                + bf2f(gv[4])*h1.x + bf2f(gv[5])*h1.y + bf2f(gv[6])*h1.z + bf2f(gv[7])*h1.w;
        }
    }
    float res = s1 * (1.f / 128.f) + s2 * (1.f / 110.85125168440814f);
    res += __shfl_xor(res, 1); res += __shfl_xor(res, 2); res += __shfl_xor(res, 4);
    if (e < ETT && sub == 0) tp[e] = res;
}

// ---------------- K5: bond head, 2-stage MFMA ----------------
#define KP5 200
__global__ __launch_bounds__(256) void k5_mfma(
    const float* __restrict__ e_final, const int* __restrict__ te,
    const float* __restrict__ tp,
    const float* __restrict__ W_bh1, const float* __restrict__ b_bh1,
    const float* __restrict__ W_bh2, const float* __restrict__ b_bh2,
    float* __restrict__ out)
{
    __shared__ __align__(16) short sx[64][KP5];
    __shared__ __align__(16) short sy[64][136];
    const int tid = threadIdx.x, w = tid >> 6, lane = tid & 63, g = lane >> 4, ln = lane & 15;

    // B1 frags: x col c -> W_bh1 row (c<160 ? c+1 : (c==160 ? 0 : zero))
    short8_t bfr[6][2];
    #pragma unroll
    for (int k0 = 0; k0 < 6; ++k0)
        #pragma unroll
        for (int nf = 0; nf < 2; ++nf) {
            short8_t bb;
            #pragma unroll
            for (int j = 0; j < 8; ++j) {
                int k = k0 * 32 + g * 8 + j;
                float v = 0.f;
                if (k < 160)       v = W_bh1[(size_t)(k + 1) * 128 + w * 32 + nf * 16 + ln];
                else if (k == 160) v = W_bh1[w * 32 + nf * 16 + ln];
                bb[j] = f2bf(v);
            }
            bfr[k0][nf] = bb;
        }
    const float bias0 = b_bh1[w * 32 + ln];
    const float bias1 = b_bh1[w * 32 + 16 + ln];

    short8_t bfr2[4];
    #pragma unroll
    for (int k0 = 0; k0 < 4; ++k0) {
        short8_t bb;
        #pragma unroll
        for (int j = 0; j < 8; ++j) {
            int k = k0 * 32 + g * 8 + j;
            bb[j] = (ln < 8) ? f2bf(W_bh2[k * 8 + ln]) : (short)0;
        }
        bfr2[k0] = bb;
    }
    const float b2o = (ln < 8) ? b_bh2[ln] : 0.f;

    const int base = blockIdx.x * 64;
    // zero pad cols 161..199
    for (int idx = tid; idx < 64 * 39; idx += 256) {
        int rr = idx / 39, c = 161 + idx % 39;
        sx[rr][c] = 0;
    }
    // stage e_final rows (gathered via te)
    {
        const int e = tid >> 2, q = tid & 3;
        const int ge = base + e;
        const bool valid = (ge < ETT);
        const int gid = valid ? te[ge] : 0;
        #pragma unroll
        for (int i = 0; i < 10; ++i) {
            float4 v = make_float4(0.f, 0.f, 0.f, 0.f);
            if (valid) v = *(const float4*)&e_final[(size_t)gid * EFW + q * 40 + i * 4];
            short4 s4; s4.x = f2bf(v.x); s4.y = f2bf(v.y); s4.z = f2bf(v.z); s4.w = f2bf(v.w);
            *(short4*)&sx[e][q * 40 + i * 4] = s4;
        }
    }
    if (tid < 64) {
        int ge = base + tid;
        sx[tid][160] = f2bf((ge < ETT) ? tp[ge] : 0.f);
    }
    __syncthreads();

    f32x4 acc[4][2];
    #pragma unroll
    for (int mf = 0; mf < 4; ++mf)
        #pragma unroll
        for (int nf = 0; nf < 2; ++nf)
            acc[mf][nf] = (f32x4){0.f, 0.f, 0.f, 0.f};
    #pragma unroll
    for (int k0 = 0; k0 < 6; ++k0) {
        short8_t a[4];
        #pragma unroll
        for (int mf = 0; mf < 4; ++mf)
            a[mf] = *(const short8_t*)&sx[mf * 16 + ln][k0 * 32 + g * 8];
        #pragma unroll
        for (int mf = 0; mf < 4; ++mf)
            #pragma unroll
            for (int nf = 0; nf < 2; ++nf)
                acc[mf][nf] = __builtin_amdgcn_mfma_f32_16x16x32_bf16(
                    a[mf], bfr[k0][nf], acc[mf][nf], 0, 0, 0);
    }
    // silu -> sy (bf16)
    #pragma unroll
    for (int mf = 0; mf < 4; ++mf)
        #pragma unroll
        for (int nf = 0; nf < 2; ++nf)
            #pragma unroll
            for (int r = 0; r < 4; ++r)
                sy[mf * 16 + g * 4 + r][w * 32 + nf * 16 + ln] =
                    f2bf(silu_f(acc[mf][nf][r] + (nf ? bias1 : bias0)));
    __syncthreads();

    f32x4 z = (f32x4){0.f, 0.f, 0.f, 0.f};
    #pragma unroll
    for (int k0 = 0; k0 < 4; ++k0) {
        short8_t a2 = *(const short8_t*)&sy[w * 16 + ln][k0 * 32 + g * 8];
        z = __builtin_amdgcn_mfma_f32_16x16x32_bf16(a2, bfr2[k0], z, 0, 0, 0);
    }
    #pragma unroll
    for (int r = 0; r < 4; ++r) {
        int e = base + w * 16 + g * 4 + r;
        if (ln < 8 && e < ETT) out[(size_t)e * 8 + ln] = z[r] + b2o;
    }
}

// ---------------- K6: predicted_r0 gather ----------------
__global__ void k6_r0(const float* __restrict__ r_t, const float* __restrict__ delta,
                      const int* __restrict__ tn, float* __restrict__ out)
{
    int i = blockIdx.x * 256 + threadIdx.x;
    if (i < NTT * 3) {
        int t = i / 3, d = i - t * 3;
        int n = tn[t];
        out[i] = r_t[n * 3 + d] + delta[n * 3 + d];
    }
}

extern "C" void kernel_launch(void* const* d_in, const int* in_sizes, int n_in,
                              void* d_out, int out_size, void* d_ws, size_t ws_size,
                              hipStream_t stream)
{
    const float* h_final = (const float*)d_in[0];
    const float* e_final = (const float*)d_in[1];
    const float* r_t     = (const float*)d_in[2];
    const int*   tn      = (const int*)d_in[3];
    const int*   te      = (const int*)d_in[4];
    const int*   ei      = (const int*)d_in[5];
    const float* W_nsp   = (const float*)d_in[6];
    const float* b_nsp   = (const float*)d_in[7];
    const float* W_at1   = (const float*)d_in[8];
    const float* b_at1   = (const float*)d_in[9];
    const float* W_at2   = (const float*)d_in[10];
    const float* b_at2   = (const float*)d_in[11];
    const float* W_left  = (const float*)d_in[12];
    const float* b_left  = (const float*)d_in[13];
    const float* W_right = (const float*)d_in[14];
    const float* b_right = (const float*)d_in[15];
    const float* W_el1   = (const float*)d_in[16];
    const float* b_el1   = (const float*)d_in[17];
    const float* ln_g    = (const float*)d_in[18];
    const float* ln_b    = (const float*)d_in[19];
    const float* W_el2   = (const float*)d_in[20];
    const float* b_el2   = (const float*)d_in[21];
    const float* w_tp0   = (const float*)d_in[22];
    const float* w_tp1   = (const float*)d_in[23];
    const float* W_bh1   = (const float*)d_in[24];
    const float* b_bh1   = (const float*)d_in[25];
    const float* W_bh2   = (const float*)d_in[26];
    const float* b_bh2   = (const float*)d_in[27];

    float* ws    = (float*)d_ws;
    float* Wl    = ws;                        // 16384
    float* bl    = Wl + 16384;                // 128
    float* Wr    = bl + 128;                  // 16384
    float* br    = Wr + 16384;                // 128  -> 33024
    short* hlb   = (short*)(ws + 33024);      // 50000*128 bf16 = 3.2M floats
    short* hrb   = (short*)(ws + 33024 + 3200000);
    float* delta = ws + 33024 + 6400000;      // 150000
    float* tpb   = delta + 150000;            // 100000
    float* gvend = tpb + 100000;
    short* Gvb   = (short*)gvend;             // 50000*192 bf16 = 4.8M floats
    short* Gb    = hlb;                       // alias hlb after k3 done

    float* out      = (float*)d_out;
    float* out_atom = out;                    // 10000*32
    float* out_r0   = out + 320000;           // 10000*3
    float* out_bond = out + 350000;           // 100000*8

    k0_combine<<<64, 256, 0, stream>>>(W_nsp, b_nsp, W_left, b_left, W_right, b_right,
                                       Wl, bl, Wr, br);
    k1_mfma<<<782, 256, 0, stream>>>(h_final, Wl, bl, Wr, br, hlb, hrb);
    k2_atom<<<256, 256, 0, stream>>>(h_final, tn, W_nsp, b_nsp, W_at1, b_at1,
                                     W_at2, b_at2, out_atom);
    hipMemsetAsync(delta, 0, 150000 * sizeof(float), stream);
    k3_edge_mfma<<<1024, 256, 0, stream>>>(e_final, ei, hlb, hrb, r_t, W_el1, b_el1,
                                           ln_g, ln_b, W_el2, b_el2, delta);
    k6_r0<<<(NTT * 3 + 255) / 256, 256, 0, stream>>>(r_t, delta, tn, out_r0);
    // k4a aliases Gb onto hlb: must run after k3 (stream-ordered)
    k4a_g<<<782, 256, 0, stream>>>(h_final, w_tp0, Gb);
    k4b_gv<<<2048, 256, 0, stream>>>(h_final, w_tp1, Gvb);
    k4c_dot<<<3125, 256, 0, stream>>>(h_final, ei, te, Gb, Gvb, tpb);
    k5_mfma<<<1563, 256, 0, stream>>>(e_final, te, tpb, W_bh1, b_bh1, W_bh2, b_bh2, out_bond);
}